// Round 5
// baseline (118.773 us; speedup 1.0000x reference)
//
#include <hip/hip_runtime.h>

// SVDLayer: per-batch Kabsch rotation (no reflection fix).
// r_est = V U^T = K^{-1/2} H^T, K = H^T H (SPD), K^{-1/2} via fp32 Newton-Schulz.
//
// R5 structure: persistent pipeline. 1024 blocks x 4 batches/block (grid fully
// co-resident: 4 blocks/CU, LDS ~25KB). Per batch: regs->LDS, sync, ISSUE next
// batch's global loads (latency hides under compute), LDS-transpose read,
// butterfly reduce, cross-wave combine. All 4 tails run in parallel (threads
// 0..3) once at the end.

constexpr int NPTS    = 1024;
constexpr int THREADS = 256;
constexpr int NF4     = NPTS * 3 / 4;   // 768 float4 per batch per array
constexpr int BPB     = 4;              // batches per block

__global__ __launch_bounds__(THREADS) void svd_layer_kernel(
    const float* __restrict__ cors,
    const float* __restrict__ p_src,
    float* __restrict__ out)
{
    __shared__ float4 lds_s[NF4];
    __shared__ float4 lds_c[NF4];
    __shared__ float  red[4][15];
    __shared__ float  allS[BPB][15];

    const int t = threadIdx.x;
    const int wave = t >> 6, lane = t & 63;
    const int b0 = blockIdx.x * BPB;

    const float4* s4 = reinterpret_cast<const float4*>(p_src) + (size_t)b0 * NF4;
    const float4* c4 = reinterpret_cast<const float4*>(cors)  + (size_t)b0 * NF4;

    // prefetch batch 0 (coalesced: 1KiB per wave per instruction)
    float4 a0 = s4[t], a1 = s4[t + 256], a2 = s4[t + 512];
    float4 d0 = c4[t], d1 = c4[t + 256], d2 = c4[t + 512];

    for (int k = 0; k < BPB; ++k) {
        // stage current batch (vmcnt wait for the prefetch lands here)
        lds_s[t] = a0; lds_s[t + 256] = a1; lds_s[t + 512] = a2;
        lds_c[t] = d0; lds_c[t + 256] = d1; lds_c[t + 512] = d2;
        __syncthreads();

        // issue next batch's loads; their wait is next iteration's LDS write
        if (k + 1 < BPB) {
            const float4* sn = s4 + (size_t)(k + 1) * NF4;
            const float4* cn = c4 + (size_t)(k + 1) * NF4;
            a0 = sn[t]; a1 = sn[t + 256]; a2 = sn[t + 512];
            d0 = cn[t]; d1 = cn[t + 256]; d2 = cn[t + 512];
        }

        // per-point view: thread t owns 4 points = 3 consecutive float4s
        const float4 t0 = lds_s[t*3+0], t1 = lds_s[t*3+1], t2 = lds_s[t*3+2];
        const float4 u0 = lds_c[t*3+0], u1 = lds_c[t*3+1], u2 = lds_c[t*3+2];

        // unpack [x y z x][y z x y][z x y z] -> 4 points
        const float sx[4] = {t0.x, t0.w, t1.z, t2.y};
        const float sy[4] = {t0.y, t1.x, t1.w, t2.z};
        const float sz[4] = {t0.z, t1.y, t2.x, t2.w};
        const float px[4] = {sx[0]+u0.x, sx[1]+u0.w, sx[2]+u1.z, sx[3]+u2.y};
        const float py[4] = {sy[0]+u0.y, sy[1]+u1.x, sy[2]+u1.w, sy[3]+u2.z};
        const float pz[4] = {sz[0]+u0.z, sz[1]+u1.y, sz[2]+u2.x, sz[3]+u2.w};

        float acc[15];
        #pragma unroll
        for (int i = 0; i < 15; ++i) acc[i] = 0.f;
        #pragma unroll
        for (int q = 0; q < 4; ++q) {
            acc[0]  += sx[q]; acc[1]  += sy[q]; acc[2]  += sz[q];
            acc[3]  += px[q]; acc[4]  += py[q]; acc[5]  += pz[q];
            acc[6]  += sx[q]*px[q]; acc[7]  += sx[q]*py[q]; acc[8]  += sx[q]*pz[q];
            acc[9]  += sy[q]*px[q]; acc[10] += sy[q]*py[q]; acc[11] += sy[q]*pz[q];
            acc[12] += sz[q]*px[q]; acc[13] += sz[q]*py[q]; acc[14] += sz[q]*pz[q];
        }

        // 64-lane butterfly reduce
        #pragma unroll
        for (int off = 32; off > 0; off >>= 1) {
            #pragma unroll
            for (int i = 0; i < 15; ++i) acc[i] += __shfl_down(acc[i], off, 64);
        }

        if (lane == 0) {
            #pragma unroll
            for (int i = 0; i < 15; ++i) red[wave][i] = acc[i];
        }
        __syncthreads();
        // cross-wave combine (15 threads); red is safely re-written only after
        // the NEXT iteration's barrier, which orders this read before it
        if (t < 15) allS[k][t] = red[0][t] + red[1][t] + red[2][t] + red[3][t];
    }

    __syncthreads();
    if (t >= BPB) return;

    // -------- threads 0..3: fp32 3x3 tails, one batch each, in parallel ----
    float S[15];
    #pragma unroll
    for (int i = 0; i < 15; ++i) S[i] = allS[t][i];

    const float invN = 1.0f / (float)NPTS;
    const float cs[3] = {S[0]*invN, S[1]*invN, S[2]*invN};
    const float cp[3] = {S[3]*invN, S[4]*invN, S[5]*invN};

    float Hm[3][3];
    #pragma unroll
    for (int i = 0; i < 3; ++i)
        #pragma unroll
        for (int j = 0; j < 3; ++j)
            Hm[i][j] = S[6 + i*3 + j] - (float)NPTS * cs[i] * cp[j];

    float K[3][3];
    #pragma unroll
    for (int i = 0; i < 3; ++i)
        #pragma unroll
        for (int j = 0; j < 3; ++j)
            K[i][j] = Hm[0][i]*Hm[0][j] + Hm[1][i]*Hm[1][j] + Hm[2][i]*Hm[2][j];

    const float tr3 = (K[0][0] + K[1][1] + K[2][2]) * (1.0f/3.0f);
    const float is  = 1.0f / fmaxf(tr3, 1e-30f);

    float Y[3][3], Z[3][3];
    #pragma unroll
    for (int i = 0; i < 3; ++i)
        #pragma unroll
        for (int j = 0; j < 3; ++j) {
            Y[i][j] = K[i][j] * is;
            Z[i][j] = (i == j) ? 1.0f : 0.0f;
        }

    // coupled Newton-Schulz: Y->A^{1/2}, Z->A^{-1/2}
    #pragma unroll
    for (int it = 0; it < 6; ++it) {
        float W[3][3];
        #pragma unroll
        for (int i = 0; i < 3; ++i)
            #pragma unroll
            for (int j = 0; j < 3; ++j) {
                float w = Z[i][0]*Y[0][j] + Z[i][1]*Y[1][j] + Z[i][2]*Y[2][j];
                W[i][j] = ((i == j) ? 1.5f : 0.0f) - 0.5f * w;
            }
        float Yn[3][3], Zn[3][3];
        #pragma unroll
        for (int i = 0; i < 3; ++i)
            #pragma unroll
            for (int j = 0; j < 3; ++j) {
                Yn[i][j] = Y[i][0]*W[0][j] + Y[i][1]*W[1][j] + Y[i][2]*W[2][j];
                Zn[i][j] = W[i][0]*Z[0][j] + W[i][1]*Z[1][j] + W[i][2]*Z[2][j];
            }
        #pragma unroll
        for (int i = 0; i < 3; ++i)
            #pragma unroll
            for (int j = 0; j < 3; ++j) { Y[i][j] = Yn[i][j]; Z[i][j] = Zn[i][j]; }
    }

    // R = (Z/sqrt(tr3)) * H^T ; t = cp - R cs
    const float rs = rsqrtf(fmaxf(tr3, 1e-30f));
    float R[3][3];
    #pragma unroll
    for (int i = 0; i < 3; ++i)
        #pragma unroll
        for (int j = 0; j < 3; ++j)
            R[i][j] = (Z[i][0]*Hm[j][0] + Z[i][1]*Hm[j][1] + Z[i][2]*Hm[j][2]) * rs;

    const float tx = cp[0] - (R[0][0]*cs[0] + R[0][1]*cs[1] + R[0][2]*cs[2]);
    const float ty = cp[1] - (R[1][0]*cs[0] + R[1][1]*cs[1] + R[1][2]*cs[2]);
    const float tz = cp[2] - (R[2][0]*cs[0] + R[2][1]*cs[1] + R[2][2]*cs[2]);

    float4* o4 = reinterpret_cast<float4*>(out + (size_t)(b0 + t) * 16);
    o4[0] = make_float4(R[0][0], R[0][1], R[0][2], tx);
    o4[1] = make_float4(R[1][0], R[1][1], R[1][2], ty);
    o4[2] = make_float4(R[2][0], R[2][1], R[2][2], tz);
    o4[3] = make_float4(0.f, 0.f, 0.f, 1.f);
}

extern "C" void kernel_launch(void* const* d_in, const int* in_sizes, int n_in,
                              void* d_out, int out_size, void* d_ws, size_t ws_size,
                              hipStream_t stream)
{
    const float* cors  = (const float*)d_in[0];
    const float* p_src = (const float*)d_in[1];
    float* out = (float*)d_out;
    const int B = in_sizes[0] / (NPTS * 3);   // 4096
    const int grid = B / BPB;                 // 1024 (fully co-resident)
    hipLaunchKernelGGL(svd_layer_kernel, dim3(grid), dim3(THREADS), 0, stream,
                       cors, p_src, out);
}

// Round 6
// 116.485 us; speedup vs baseline: 1.0196x; 1.0196x over previous
//
#include <hip/hip_runtime.h>

// SVDLayer: per-batch Kabsch rotation (no reflection fix).
// r_est = V U^T = K^{-1/2} H^T, K = H^T H (SPD), K^{-1/2} via fp32 Newton-Schulz.
//
// R6: cut wave-reduction DS traffic 90 -> 16 ops/thread/batch.
//  - stages xor1/xor2 via DPP quad_perm adds (VALU pipe, no DS)
//  - free repack: lane c=lane&3 keeps values 4c..4c+3 (all lanes of a quad
//    hold identical quad-sums after the DPP stages)
//  - 4 values x 4 shfl_xor (off 4,8,16,32) finish the 64-lane reduce
//  - per-wave partials go to wave-private allS slots (no per-iter combine
//    barrier); tails sum 4 wave-partials
//  - BPB=2, grid 2048 -> 6 blocks/CU resident (LDS 24.5KB/block)

constexpr int NPTS    = 1024;
constexpr int THREADS = 256;
constexpr int NF4     = NPTS * 3 / 4;   // 768 float4 per batch per array
constexpr int BPB     = 2;              // batches per block

__device__ __forceinline__ float dpp_qxor1(float x) {   // lane ^ 1 within quad
    int y = __builtin_amdgcn_update_dpp(0, __float_as_int(x), 0xB1, 0xF, 0xF, true);
    return __int_as_float(y);
}
__device__ __forceinline__ float dpp_qxor2(float x) {   // lane ^ 2 within quad
    int y = __builtin_amdgcn_update_dpp(0, __float_as_int(x), 0x4E, 0xF, 0xF, true);
    return __int_as_float(y);
}

__global__ __launch_bounds__(THREADS) void svd_layer_kernel(
    const float* __restrict__ cors,
    const float* __restrict__ p_src,
    float* __restrict__ out)
{
    __shared__ float4 lds_s[NF4];
    __shared__ float4 lds_c[NF4];
    __shared__ float  allS[BPB][4][16];   // [batch][wave][15 sums + pad]

    const int t = threadIdx.x;
    const int wave = t >> 6, lane = t & 63;
    const int b0 = blockIdx.x * BPB;

    const float4* s4 = reinterpret_cast<const float4*>(p_src) + (size_t)b0 * NF4;
    const float4* c4 = reinterpret_cast<const float4*>(cors)  + (size_t)b0 * NF4;

    // prefetch batch 0 (coalesced: 1KiB per wave per instruction)
    float4 a0 = s4[t], a1 = s4[t + 256], a2 = s4[t + 512];
    float4 d0 = c4[t], d1 = c4[t + 256], d2 = c4[t + 512];

    for (int k = 0; k < BPB; ++k) {
        // stage current batch
        lds_s[t] = a0; lds_s[t + 256] = a1; lds_s[t + 512] = a2;
        lds_c[t] = d0; lds_c[t + 256] = d1; lds_c[t + 512] = d2;
        __syncthreads();

        // issue next batch's loads (latency hides under compute)
        if (k + 1 < BPB) {
            const float4* sn = s4 + (size_t)(k + 1) * NF4;
            const float4* cn = c4 + (size_t)(k + 1) * NF4;
            a0 = sn[t]; a1 = sn[t + 256]; a2 = sn[t + 512];
            d0 = cn[t]; d1 = cn[t + 256]; d2 = cn[t + 512];
        }

        // per-point view: thread t owns 4 points = 3 consecutive float4s
        const float4 t0 = lds_s[t*3+0], t1 = lds_s[t*3+1], t2 = lds_s[t*3+2];
        const float4 u0 = lds_c[t*3+0], u1 = lds_c[t*3+1], u2 = lds_c[t*3+2];
        __syncthreads();   // after this, next iteration may overwrite lds_s/c

        // unpack [x y z x][y z x y][z x y z] -> 4 points
        const float sx[4] = {t0.x, t0.w, t1.z, t2.y};
        const float sy[4] = {t0.y, t1.x, t1.w, t2.z};
        const float sz[4] = {t0.z, t1.y, t2.x, t2.w};
        const float px[4] = {sx[0]+u0.x, sx[1]+u0.w, sx[2]+u1.z, sx[3]+u2.y};
        const float py[4] = {sy[0]+u0.y, sy[1]+u1.x, sy[2]+u1.w, sy[3]+u2.z};
        const float pz[4] = {sz[0]+u0.z, sz[1]+u1.y, sz[2]+u2.x, sz[3]+u2.w};

        float acc[15];
        #pragma unroll
        for (int i = 0; i < 15; ++i) acc[i] = 0.f;
        #pragma unroll
        for (int q = 0; q < 4; ++q) {
            acc[0]  += sx[q]; acc[1]  += sy[q]; acc[2]  += sz[q];
            acc[3]  += px[q]; acc[4]  += py[q]; acc[5]  += pz[q];
            acc[6]  += sx[q]*px[q]; acc[7]  += sx[q]*py[q]; acc[8]  += sx[q]*pz[q];
            acc[9]  += sy[q]*px[q]; acc[10] += sy[q]*py[q]; acc[11] += sy[q]*pz[q];
            acc[12] += sz[q]*px[q]; acc[13] += sz[q]*py[q]; acc[14] += sz[q]*pz[q];
        }

        // quad reduce via DPP (VALU pipe): all 4 lanes of a quad get quad-sum
        #pragma unroll
        for (int i = 0; i < 15; ++i) acc[i] += dpp_qxor1(acc[i]);
        #pragma unroll
        for (int i = 0; i < 15; ++i) acc[i] += dpp_qxor2(acc[i]);

        // free repack: lane c keeps values 4c..4c+3 (static selects)
        const int c = lane & 3;
        float r0 = (c==0)?acc[0]:(c==1)?acc[4]:(c==2)?acc[8] :acc[12];
        float r1 = (c==0)?acc[1]:(c==1)?acc[5]:(c==2)?acc[9] :acc[13];
        float r2 = (c==0)?acc[2]:(c==1)?acc[6]:(c==2)?acc[10]:acc[14];
        float r3 = (c==0)?acc[3]:(c==1)?acc[7]:(c==2)?acc[11]:0.f;

        // finish reduce across quads: 4 values x 4 steps = 16 shuffles
        #pragma unroll
        for (int off = 4; off <= 32; off <<= 1) {
            r0 += __shfl_xor(r0, off, 64);
            r1 += __shfl_xor(r1, off, 64);
            r2 += __shfl_xor(r2, off, 64);
            r3 += __shfl_xor(r3, off, 64);
        }

        // lanes 0..3 hold full wave-sums for their residue; wave-private write
        if (lane < 4) {
            float* dst = &allS[k][wave][lane * 4];
            dst[0] = r0; dst[1] = r1; dst[2] = r2; dst[3] = r3;
        }
    }

    __syncthreads();
    if (t >= BPB) return;

    // -------- threads 0..BPB-1: fp32 3x3 tails, one batch each --------
    float S[15];
    #pragma unroll
    for (int i = 0; i < 15; ++i)
        S[i] = allS[t][0][i] + allS[t][1][i] + allS[t][2][i] + allS[t][3][i];

    const float invN = 1.0f / (float)NPTS;
    const float cs[3] = {S[0]*invN, S[1]*invN, S[2]*invN};
    const float cp[3] = {S[3]*invN, S[4]*invN, S[5]*invN};

    float Hm[3][3];
    #pragma unroll
    for (int i = 0; i < 3; ++i)
        #pragma unroll
        for (int j = 0; j < 3; ++j)
            Hm[i][j] = S[6 + i*3 + j] - (float)NPTS * cs[i] * cp[j];

    float K[3][3];
    #pragma unroll
    for (int i = 0; i < 3; ++i)
        #pragma unroll
        for (int j = 0; j < 3; ++j)
            K[i][j] = Hm[0][i]*Hm[0][j] + Hm[1][i]*Hm[1][j] + Hm[2][i]*Hm[2][j];

    const float tr3 = (K[0][0] + K[1][1] + K[2][2]) * (1.0f/3.0f);
    const float is  = 1.0f / fmaxf(tr3, 1e-30f);

    float Y[3][3], Z[3][3];
    #pragma unroll
    for (int i = 0; i < 3; ++i)
        #pragma unroll
        for (int j = 0; j < 3; ++j) {
            Y[i][j] = K[i][j] * is;
            Z[i][j] = (i == j) ? 1.0f : 0.0f;
        }

    // coupled Newton-Schulz: Y->A^{1/2}, Z->A^{-1/2}
    #pragma unroll
    for (int it = 0; it < 6; ++it) {
        float W[3][3];
        #pragma unroll
        for (int i = 0; i < 3; ++i)
            #pragma unroll
            for (int j = 0; j < 3; ++j) {
                float w = Z[i][0]*Y[0][j] + Z[i][1]*Y[1][j] + Z[i][2]*Y[2][j];
                W[i][j] = ((i == j) ? 1.5f : 0.0f) - 0.5f * w;
            }
        float Yn[3][3], Zn[3][3];
        #pragma unroll
        for (int i = 0; i < 3; ++i)
            #pragma unroll
            for (int j = 0; j < 3; ++j) {
                Yn[i][j] = Y[i][0]*W[0][j] + Y[i][1]*W[1][j] + Y[i][2]*W[2][j];
                Zn[i][j] = W[i][0]*Z[0][j] + W[i][1]*Z[1][j] + W[i][2]*Z[2][j];
            }
        #pragma unroll
        for (int i = 0; i < 3; ++i)
            #pragma unroll
            for (int j = 0; j < 3; ++j) { Y[i][j] = Yn[i][j]; Z[i][j] = Zn[i][j]; }
    }

    // R = (Z/sqrt(tr3)) * H^T ; t = cp - R cs
    const float rs = rsqrtf(fmaxf(tr3, 1e-30f));
    float R[3][3];
    #pragma unroll
    for (int i = 0; i < 3; ++i)
        #pragma unroll
        for (int j = 0; j < 3; ++j)
            R[i][j] = (Z[i][0]*Hm[j][0] + Z[i][1]*Hm[j][1] + Z[i][2]*Hm[j][2]) * rs;

    const float tx = cp[0] - (R[0][0]*cs[0] + R[0][1]*cs[1] + R[0][2]*cs[2]);
    const float ty = cp[1] - (R[1][0]*cs[0] + R[1][1]*cs[1] + R[1][2]*cs[2]);
    const float tz = cp[2] - (R[2][0]*cs[0] + R[2][1]*cs[1] + R[2][2]*cs[2]);

    float4* o4 = reinterpret_cast<float4*>(out + (size_t)(b0 + t) * 16);
    o4[0] = make_float4(R[0][0], R[0][1], R[0][2], tx);
    o4[1] = make_float4(R[1][0], R[1][1], R[1][2], ty);
    o4[2] = make_float4(R[2][0], R[2][1], R[2][2], tz);
    o4[3] = make_float4(0.f, 0.f, 0.f, 1.f);
}

extern "C" void kernel_launch(void* const* d_in, const int* in_sizes, int n_in,
                              void* d_out, int out_size, void* d_ws, size_t ws_size,
                              hipStream_t stream)
{
    const float* cors  = (const float*)d_in[0];
    const float* p_src = (const float*)d_in[1];
    float* out = (float*)d_out;
    const int B = in_sizes[0] / (NPTS * 3);   // 4096
    const int grid = B / BPB;                 // 2048
    hipLaunchKernelGGL(svd_layer_kernel, dim3(grid), dim3(THREADS), 0, stream,
                       cors, p_src, out);
}

// Round 7
// 115.230 us; speedup vs baseline: 1.0307x; 1.0109x over previous
//
#include <hip/hip_runtime.h>

// SVDLayer: per-batch Kabsch rotation (no reflection fix).
// r_est = V U^T = K^{-1/2} H^T, K = H^T H (SPD), K^{-1/2} via fp32 Newton-Schulz.
//
// R7: NO LDS staging. Each thread loads whole points as float3 (dwordx3):
// lane stride 12B -> a wave reads a dense 768B window (perfect coalescing,
// zero waste), so the transpose that forced LDS staging vanishes.
// 8 independent loads/thread, DPP-quad + 16 shfl_xor reduce (verified R6),
// 256B LDS for cross-wave combine, thread-0 Newton-Schulz tail (verified).

constexpr int NPTS    = 1024;
constexpr int THREADS = 256;

struct F3 { float x, y, z; };   // 12B; loads lower to global_load_dwordx3

__device__ __forceinline__ float dpp_qxor1(float x) {   // lane ^ 1 within quad
    int y = __builtin_amdgcn_update_dpp(0, __float_as_int(x), 0xB1, 0xF, 0xF, true);
    return __int_as_float(y);
}
__device__ __forceinline__ float dpp_qxor2(float x) {   // lane ^ 2 within quad
    int y = __builtin_amdgcn_update_dpp(0, __float_as_int(x), 0x4E, 0xF, 0xF, true);
    return __int_as_float(y);
}

__global__ __launch_bounds__(THREADS) void svd_layer_kernel(
    const float* __restrict__ cors,
    const float* __restrict__ p_src,
    float* __restrict__ out)
{
    __shared__ float allS[4][16];   // [wave][15 sums + pad]

    const int b = blockIdx.x;
    const int t = threadIdx.x;
    const int wave = t >> 6, lane = t & 63;
    const size_t base = (size_t)b * NPTS * 3;

    const F3* sp = reinterpret_cast<const F3*>(p_src + base);
    const F3* cq = reinterpret_cast<const F3*>(cors  + base);

    // 8 independent dwordx3 loads: 4 points (src+cors) per thread
    const F3 s0 = sp[t], s1 = sp[t + 256], s2 = sp[t + 512], s3 = sp[t + 768];
    const F3 c0 = cq[t], c1 = cq[t + 256], c2 = cq[t + 512], c3 = cq[t + 768];

    const float sx[4] = {s0.x, s1.x, s2.x, s3.x};
    const float sy[4] = {s0.y, s1.y, s2.y, s3.y};
    const float sz[4] = {s0.z, s1.z, s2.z, s3.z};
    const float px[4] = {s0.x + c0.x, s1.x + c1.x, s2.x + c2.x, s3.x + c3.x};
    const float py[4] = {s0.y + c0.y, s1.y + c1.y, s2.y + c2.y, s3.y + c3.y};
    const float pz[4] = {s0.z + c0.z, s1.z + c1.z, s2.z + c2.z, s3.z + c3.z};

    // 15 partials: Σsrc(3), Σpred(3), Σ src_i*pred_j (9)
    float acc[15];
    #pragma unroll
    for (int i = 0; i < 15; ++i) acc[i] = 0.f;
    #pragma unroll
    for (int q = 0; q < 4; ++q) {
        acc[0]  += sx[q]; acc[1]  += sy[q]; acc[2]  += sz[q];
        acc[3]  += px[q]; acc[4]  += py[q]; acc[5]  += pz[q];
        acc[6]  += sx[q]*px[q]; acc[7]  += sx[q]*py[q]; acc[8]  += sx[q]*pz[q];
        acc[9]  += sy[q]*px[q]; acc[10] += sy[q]*py[q]; acc[11] += sy[q]*pz[q];
        acc[12] += sz[q]*px[q]; acc[13] += sz[q]*py[q]; acc[14] += sz[q]*pz[q];
    }

    // quad reduce via DPP (VALU pipe): all 4 lanes of a quad get quad-sum
    #pragma unroll
    for (int i = 0; i < 15; ++i) acc[i] += dpp_qxor1(acc[i]);
    #pragma unroll
    for (int i = 0; i < 15; ++i) acc[i] += dpp_qxor2(acc[i]);

    // free repack: lane c keeps values 4c..4c+3 (static selects)
    const int c = lane & 3;
    float r0 = (c==0)?acc[0]:(c==1)?acc[4]:(c==2)?acc[8] :acc[12];
    float r1 = (c==0)?acc[1]:(c==1)?acc[5]:(c==2)?acc[9] :acc[13];
    float r2 = (c==0)?acc[2]:(c==1)?acc[6]:(c==2)?acc[10]:acc[14];
    float r3 = (c==0)?acc[3]:(c==1)?acc[7]:(c==2)?acc[11]:0.f;

    // finish reduce across quads: 4 values x 4 steps = 16 shuffles
    #pragma unroll
    for (int off = 4; off <= 32; off <<= 1) {
        r0 += __shfl_xor(r0, off, 64);
        r1 += __shfl_xor(r1, off, 64);
        r2 += __shfl_xor(r2, off, 64);
        r3 += __shfl_xor(r3, off, 64);
    }

    // lanes 0..3 hold full wave-sums for their residue
    if (lane < 4) {
        float* dst = &allS[wave][lane * 4];
        dst[0] = r0; dst[1] = r1; dst[2] = r2; dst[3] = r3;
    }
    __syncthreads();
    if (t != 0) return;

    // -------- thread 0: fp32 3x3 tail --------
    float S[15];
    #pragma unroll
    for (int i = 0; i < 15; ++i)
        S[i] = allS[0][i] + allS[1][i] + allS[2][i] + allS[3][i];

    const float invN = 1.0f / (float)NPTS;
    const float cs[3] = {S[0]*invN, S[1]*invN, S[2]*invN};
    const float cp[3] = {S[3]*invN, S[4]*invN, S[5]*invN};

    float Hm[3][3];
    #pragma unroll
    for (int i = 0; i < 3; ++i)
        #pragma unroll
        for (int j = 0; j < 3; ++j)
            Hm[i][j] = S[6 + i*3 + j] - (float)NPTS * cs[i] * cp[j];

    float K[3][3];
    #pragma unroll
    for (int i = 0; i < 3; ++i)
        #pragma unroll
        for (int j = 0; j < 3; ++j)
            K[i][j] = Hm[0][i]*Hm[0][j] + Hm[1][i]*Hm[1][j] + Hm[2][i]*Hm[2][j];

    const float tr3 = (K[0][0] + K[1][1] + K[2][2]) * (1.0f/3.0f);
    const float is  = 1.0f / fmaxf(tr3, 1e-30f);

    float Y[3][3], Z[3][3];
    #pragma unroll
    for (int i = 0; i < 3; ++i)
        #pragma unroll
        for (int j = 0; j < 3; ++j) {
            Y[i][j] = K[i][j] * is;
            Z[i][j] = (i == j) ? 1.0f : 0.0f;
        }

    // coupled Newton-Schulz: Y->A^{1/2}, Z->A^{-1/2}
    #pragma unroll
    for (int it = 0; it < 6; ++it) {
        float W[3][3];
        #pragma unroll
        for (int i = 0; i < 3; ++i)
            #pragma unroll
            for (int j = 0; j < 3; ++j) {
                float w = Z[i][0]*Y[0][j] + Z[i][1]*Y[1][j] + Z[i][2]*Y[2][j];
                W[i][j] = ((i == j) ? 1.5f : 0.0f) - 0.5f * w;
            }
        float Yn[3][3], Zn[3][3];
        #pragma unroll
        for (int i = 0; i < 3; ++i)
            #pragma unroll
            for (int j = 0; j < 3; ++j) {
                Yn[i][j] = Y[i][0]*W[0][j] + Y[i][1]*W[1][j] + Y[i][2]*W[2][j];
                Zn[i][j] = W[i][0]*Z[0][j] + W[i][1]*Z[1][j] + W[i][2]*Z[2][j];
            }
        #pragma unroll
        for (int i = 0; i < 3; ++i)
            #pragma unroll
            for (int j = 0; j < 3; ++j) { Y[i][j] = Yn[i][j]; Z[i][j] = Zn[i][j]; }
    }

    // R = (Z/sqrt(tr3)) * H^T ; t = cp - R cs
    const float rs = rsqrtf(fmaxf(tr3, 1e-30f));
    float R[3][3];
    #pragma unroll
    for (int i = 0; i < 3; ++i)
        #pragma unroll
        for (int j = 0; j < 3; ++j)
            R[i][j] = (Z[i][0]*Hm[j][0] + Z[i][1]*Hm[j][1] + Z[i][2]*Hm[j][2]) * rs;

    const float tx = cp[0] - (R[0][0]*cs[0] + R[0][1]*cs[1] + R[0][2]*cs[2]);
    const float ty = cp[1] - (R[1][0]*cs[0] + R[1][1]*cs[1] + R[1][2]*cs[2]);
    const float tz = cp[2] - (R[2][0]*cs[0] + R[2][1]*cs[1] + R[2][2]*cs[2]);

    float4* o4 = reinterpret_cast<float4*>(out + (size_t)b * 16);
    o4[0] = make_float4(R[0][0], R[0][1], R[0][2], tx);
    o4[1] = make_float4(R[1][0], R[1][1], R[1][2], ty);
    o4[2] = make_float4(R[2][0], R[2][1], R[2][2], tz);
    o4[3] = make_float4(0.f, 0.f, 0.f, 1.f);
}

extern "C" void kernel_launch(void* const* d_in, const int* in_sizes, int n_in,
                              void* d_out, int out_size, void* d_ws, size_t ws_size,
                              hipStream_t stream)
{
    const float* cors  = (const float*)d_in[0];
    const float* p_src = (const float*)d_in[1];
    float* out = (float*)d_out;
    const int B = in_sizes[0] / (NPTS * 3);   // 4096
    hipLaunchKernelGGL(svd_layer_kernel, dim3(B), dim3(THREADS), 0, stream,
                       cors, p_src, out);
}

// Round 8
// 113.373 us; speedup vs baseline: 1.0476x; 1.0164x over previous
//
#include <hip/hip_runtime.h>

// SVDLayer: per-batch Kabsch rotation (no reflection fix).
// r_est = V U^T = K^{-1/2} H^T, K = H^T H (SPD), K^{-1/2} via fp32 Newton-Schulz.
//
// R8: single co-resident round. 2048 blocks x 256 threads (= 8 blocks/CU x 256
// CU exactly), 2 batches/block, NO staging LDS. Each thread: 16 independent
// dwordx3 loads (4 pts x {src,cors} x 2 batches) all in flight, two DPP-quad +
// 16-shfl reductions, tails on threads 0/1 in parallel.

constexpr int NPTS    = 1024;
constexpr int THREADS = 256;
constexpr int BPB     = 2;

struct F3 { float x, y, z; };   // 12B; lowers to global_load_dwordx3

__device__ __forceinline__ float dpp_qxor1(float x) {   // lane ^ 1 within quad
    int y = __builtin_amdgcn_update_dpp(0, __float_as_int(x), 0xB1, 0xF, 0xF, true);
    return __int_as_float(y);
}
__device__ __forceinline__ float dpp_qxor2(float x) {   // lane ^ 2 within quad
    int y = __builtin_amdgcn_update_dpp(0, __float_as_int(x), 0x4E, 0xF, 0xF, true);
    return __int_as_float(y);
}

__global__ __launch_bounds__(THREADS) void svd_layer_kernel(
    const float* __restrict__ cors,
    const float* __restrict__ p_src,
    float* __restrict__ out)
{
    __shared__ float allS[BPB][4][16];   // [batch][wave][15 sums + pad]

    const int t = threadIdx.x;
    const int wave = t >> 6, lane = t & 63;
    const int b0 = blockIdx.x * BPB;

    const F3* spA = reinterpret_cast<const F3*>(p_src + (size_t)b0 * NPTS * 3);
    const F3* cqA = reinterpret_cast<const F3*>(cors  + (size_t)b0 * NPTS * 3);
    const F3* spB = spA + NPTS;
    const F3* cqB = cqA + NPTS;

    // 16 independent dwordx3 loads, all issued before any use
    const F3 sA0 = spA[t], sA1 = spA[t+256], sA2 = spA[t+512], sA3 = spA[t+768];
    const F3 cA0 = cqA[t], cA1 = cqA[t+256], cA2 = cqA[t+512], cA3 = cqA[t+768];
    const F3 sB0 = spB[t], sB1 = spB[t+256], sB2 = spB[t+512], sB3 = spB[t+768];
    const F3 cB0 = cqB[t], cB1 = cqB[t+256], cB2 = cqB[t+512], cB3 = cqB[t+768];

    float accA[15], accB[15];
    #pragma unroll
    for (int i = 0; i < 15; ++i) { accA[i] = 0.f; accB[i] = 0.f; }

    {   // batch A
        const float sx[4] = {sA0.x, sA1.x, sA2.x, sA3.x};
        const float sy[4] = {sA0.y, sA1.y, sA2.y, sA3.y};
        const float sz[4] = {sA0.z, sA1.z, sA2.z, sA3.z};
        const float px[4] = {sA0.x+cA0.x, sA1.x+cA1.x, sA2.x+cA2.x, sA3.x+cA3.x};
        const float py[4] = {sA0.y+cA0.y, sA1.y+cA1.y, sA2.y+cA2.y, sA3.y+cA3.y};
        const float pz[4] = {sA0.z+cA0.z, sA1.z+cA1.z, sA2.z+cA2.z, sA3.z+cA3.z};
        #pragma unroll
        for (int q = 0; q < 4; ++q) {
            accA[0]  += sx[q]; accA[1]  += sy[q]; accA[2]  += sz[q];
            accA[3]  += px[q]; accA[4]  += py[q]; accA[5]  += pz[q];
            accA[6]  += sx[q]*px[q]; accA[7]  += sx[q]*py[q]; accA[8]  += sx[q]*pz[q];
            accA[9]  += sy[q]*px[q]; accA[10] += sy[q]*py[q]; accA[11] += sy[q]*pz[q];
            accA[12] += sz[q]*px[q]; accA[13] += sz[q]*py[q]; accA[14] += sz[q]*pz[q];
        }
    }
    {   // batch B
        const float sx[4] = {sB0.x, sB1.x, sB2.x, sB3.x};
        const float sy[4] = {sB0.y, sB1.y, sB2.y, sB3.y};
        const float sz[4] = {sB0.z, sB1.z, sB2.z, sB3.z};
        const float px[4] = {sB0.x+cB0.x, sB1.x+cB1.x, sB2.x+cB2.x, sB3.x+cB3.x};
        const float py[4] = {sB0.y+cB0.y, sB1.y+cB1.y, sB2.y+cB2.y, sB3.y+cB3.y};
        const float pz[4] = {sB0.z+cB0.z, sB1.z+cB1.z, sB2.z+cB2.z, sB3.z+cB3.z};
        #pragma unroll
        for (int q = 0; q < 4; ++q) {
            accB[0]  += sx[q]; accB[1]  += sy[q]; accB[2]  += sz[q];
            accB[3]  += px[q]; accB[4]  += py[q]; accB[5]  += pz[q];
            accB[6]  += sx[q]*px[q]; accB[7]  += sx[q]*py[q]; accB[8]  += sx[q]*pz[q];
            accB[9]  += sy[q]*px[q]; accB[10] += sy[q]*py[q]; accB[11] += sy[q]*pz[q];
            accB[12] += sz[q]*px[q]; accB[13] += sz[q]*py[q]; accB[14] += sz[q]*pz[q];
        }
    }

    // quad reduce via DPP (VALU pipe, no DS)
    #pragma unroll
    for (int i = 0; i < 15; ++i) { accA[i] += dpp_qxor1(accA[i]); accB[i] += dpp_qxor1(accB[i]); }
    #pragma unroll
    for (int i = 0; i < 15; ++i) { accA[i] += dpp_qxor2(accA[i]); accB[i] += dpp_qxor2(accB[i]); }

    // free repack: lane c keeps values 4c..4c+3
    const int c = lane & 3;
    float a0 = (c==0)?accA[0]:(c==1)?accA[4]:(c==2)?accA[8] :accA[12];
    float a1 = (c==0)?accA[1]:(c==1)?accA[5]:(c==2)?accA[9] :accA[13];
    float a2 = (c==0)?accA[2]:(c==1)?accA[6]:(c==2)?accA[10]:accA[14];
    float a3 = (c==0)?accA[3]:(c==1)?accA[7]:(c==2)?accA[11]:0.f;
    float b0r= (c==0)?accB[0]:(c==1)?accB[4]:(c==2)?accB[8] :accB[12];
    float b1r= (c==0)?accB[1]:(c==1)?accB[5]:(c==2)?accB[9] :accB[13];
    float b2r= (c==0)?accB[2]:(c==1)?accB[6]:(c==2)?accB[10]:accB[14];
    float b3r= (c==0)?accB[3]:(c==1)?accB[7]:(c==2)?accB[11]:0.f;

    // finish reduce across quads: 8 values x 4 steps (two batches interleaved)
    #pragma unroll
    for (int off = 4; off <= 32; off <<= 1) {
        a0 += __shfl_xor(a0, off, 64);  b0r += __shfl_xor(b0r, off, 64);
        a1 += __shfl_xor(a1, off, 64);  b1r += __shfl_xor(b1r, off, 64);
        a2 += __shfl_xor(a2, off, 64);  b2r += __shfl_xor(b2r, off, 64);
        a3 += __shfl_xor(a3, off, 64);  b3r += __shfl_xor(b3r, off, 64);
    }

    if (lane < 4) {
        float* dA = &allS[0][wave][lane * 4];
        dA[0] = a0;  dA[1] = a1;  dA[2] = a2;  dA[3] = a3;
        float* dB = &allS[1][wave][lane * 4];
        dB[0] = b0r; dB[1] = b1r; dB[2] = b2r; dB[3] = b3r;
    }
    __syncthreads();
    if (t >= BPB) return;

    // -------- threads 0..1: fp32 3x3 tails, one batch each --------
    float S[15];
    #pragma unroll
    for (int i = 0; i < 15; ++i)
        S[i] = allS[t][0][i] + allS[t][1][i] + allS[t][2][i] + allS[t][3][i];

    const float invN = 1.0f / (float)NPTS;
    const float cs[3] = {S[0]*invN, S[1]*invN, S[2]*invN};
    const float cp[3] = {S[3]*invN, S[4]*invN, S[5]*invN};

    float Hm[3][3];
    #pragma unroll
    for (int i = 0; i < 3; ++i)
        #pragma unroll
        for (int j = 0; j < 3; ++j)
            Hm[i][j] = S[6 + i*3 + j] - (float)NPTS * cs[i] * cp[j];

    float K[3][3];
    #pragma unroll
    for (int i = 0; i < 3; ++i)
        #pragma unroll
        for (int j = 0; j < 3; ++j)
            K[i][j] = Hm[0][i]*Hm[0][j] + Hm[1][i]*Hm[1][j] + Hm[2][i]*Hm[2][j];

    const float tr3 = (K[0][0] + K[1][1] + K[2][2]) * (1.0f/3.0f);
    const float is  = 1.0f / fmaxf(tr3, 1e-30f);

    float Y[3][3], Z[3][3];
    #pragma unroll
    for (int i = 0; i < 3; ++i)
        #pragma unroll
        for (int j = 0; j < 3; ++j) {
            Y[i][j] = K[i][j] * is;
            Z[i][j] = (i == j) ? 1.0f : 0.0f;
        }

    // coupled Newton-Schulz: Y->A^{1/2}, Z->A^{-1/2}
    #pragma unroll
    for (int it = 0; it < 6; ++it) {
        float W[3][3];
        #pragma unroll
        for (int i = 0; i < 3; ++i)
            #pragma unroll
            for (int j = 0; j < 3; ++j) {
                float w = Z[i][0]*Y[0][j] + Z[i][1]*Y[1][j] + Z[i][2]*Y[2][j];
                W[i][j] = ((i == j) ? 1.5f : 0.0f) - 0.5f * w;
            }
        float Yn[3][3], Zn[3][3];
        #pragma unroll
        for (int i = 0; i < 3; ++i)
            #pragma unroll
            for (int j = 0; j < 3; ++j) {
                Yn[i][j] = Y[i][0]*W[0][j] + Y[i][1]*W[1][j] + Y[i][2]*W[2][j];
                Zn[i][j] = W[i][0]*Z[0][j] + W[i][1]*Z[1][j] + W[i][2]*Z[2][j];
            }
        #pragma unroll
        for (int i = 0; i < 3; ++i)
            #pragma unroll
            for (int j = 0; j < 3; ++j) { Y[i][j] = Yn[i][j]; Z[i][j] = Zn[i][j]; }
    }

    // R = (Z/sqrt(tr3)) * H^T ; t = cp - R cs
    const float rs = rsqrtf(fmaxf(tr3, 1e-30f));
    float R[3][3];
    #pragma unroll
    for (int i = 0; i < 3; ++i)
        #pragma unroll
        for (int j = 0; j < 3; ++j)
            R[i][j] = (Z[i][0]*Hm[j][0] + Z[i][1]*Hm[j][1] + Z[i][2]*Hm[j][2]) * rs;

    const float tx = cp[0] - (R[0][0]*cs[0] + R[0][1]*cs[1] + R[0][2]*cs[2]);
    const float ty = cp[1] - (R[1][0]*cs[0] + R[1][1]*cs[1] + R[1][2]*cs[2]);
    const float tz = cp[2] - (R[2][0]*cs[0] + R[2][1]*cs[1] + R[2][2]*cs[2]);

    const int b = blockIdx.x * BPB + t;
    float4* o4 = reinterpret_cast<float4*>(out + (size_t)b * 16);
    o4[0] = make_float4(R[0][0], R[0][1], R[0][2], tx);
    o4[1] = make_float4(R[1][0], R[1][1], R[1][2], ty);
    o4[2] = make_float4(R[2][0], R[2][1], R[2][2], tz);
    o4[3] = make_float4(0.f, 0.f, 0.f, 1.f);
}

extern "C" void kernel_launch(void* const* d_in, const int* in_sizes, int n_in,
                              void* d_out, int out_size, void* d_ws, size_t ws_size,
                              hipStream_t stream)
{
    const float* cors  = (const float*)d_in[0];
    const float* p_src = (const float*)d_in[1];
    float* out = (float*)d_out;
    const int B = in_sizes[0] / (NPTS * 3);   // 4096
    const int grid = B / BPB;                 // 2048 = 8 blocks/CU, fully resident
    hipLaunchKernelGGL(svd_layer_kernel, dim3(grid), dim3(THREADS), 0, stream,
                       cors, p_src, out);
}